// Round 17
// baseline (165.632 us; speedup 1.0000x reference)
//
#include <hip/hip_runtime.h>

// Problem geometry (fixed by the reference)
#define SPATIAL 32768            // D*H*W
#define NB 4
#define CDIM 128
#define KCODES 1024
#define NROWS (NB * SPATIAL)     // 131072

// Output layout in d_out (all float32, concatenated in return order)
#define Q_SIZE (NB * CDIM * SPATIAL)     // 16777216
#define LOSS_OFF Q_SIZE
#define IDX_OFF (Q_SIZE + 1)
#define ESUM_OFF (IDX_OFF + NROWS)
#define EMB_OFF (ESUM_OFF + 256)

#define TCODES 32                // codes per tile (score)
#define NT (KCODES / TCODES)     // 32 tiles
#define MARGIN1 0.06f            // fp16 1-pass gap margin (proven r5/r7/r10-r16)
#define CAP1 12288
#define NCHUNK 8                 // refine_scan code chunks (128 codes each)
#define RB_ROWS 16               // refine_scan rows per block
#define EMIT_BLOCKS 2048
#define FINF 3.4e38f
#define LSCALE 1048576.0f        // 2^20 fixed-point for deterministic loss

typedef _Float16 half8 __attribute__((ext_vector_type(8)));
typedef float f32x4 __attribute__((ext_vector_type(4)));
typedef unsigned long long ull;

static __device__ __forceinline__ void gload16(const uint4* g, uint4* l) {
    __builtin_amdgcn_global_load_lds(
        (const __attribute__((address_space(1))) unsigned int*)g,
        (__attribute__((address_space(3))) unsigned int*)l, 16, 0, 0);
}

// monotone float<->uint map (total order; invertible)
static __device__ __forceinline__ unsigned ford(float f) {
    unsigned u = __float_as_uint(f);
    return (u >> 31) ? ~u : (u | 0x80000000u);
}
static __device__ __forceinline__ float finv(unsigned o) {
    unsigned u = (o & 0x80000000u) ? (o & 0x7FFFFFFFu) : ~o;
    return __uint_as_float(u);
}

// ---- prep (merged): blocks 0-63: emb -> fp16 tiles + ||e||^2 + passthrough
// + inits; blocks 64-127: emb -> ecT transpose (channel-major, for refine). --
__global__ __launch_bounds__(256) void prep_kernel(const float* __restrict__ emb,
                                                   uint4* __restrict__ Bpk16,
                                                   float* __restrict__ ecT,
                                                   float* __restrict__ esq,
                                                   float* __restrict__ out,
                                                   ull* __restrict__ loss_acc,
                                                   int* __restrict__ flag_cnt,
                                                   int* __restrict__ fin_cnt) {
    if (blockIdx.x >= 64) {
        // transpose: emb [k][c] -> ecT [c][k]
        const int k0 = (blockIdx.x - 64) * 16;
        const int l = threadIdx.x & 15;
        const int gi = threadIdx.x >> 4;
#pragma unroll
        for (int i = 0; i < 8; i++) {
            int c = gi * 8 + i;
            ecT[(size_t)c * KCODES + k0 + l] = emb[(size_t)(k0 + l) * CDIM + c];
        }
        return;
    }

    const int task = blockIdx.x * 256 + threadIdx.x;   // 16384 tasks
    const int k = task >> 4, g = task & 15;

    if (blockIdx.x == 0) {
        if (threadIdx.x == 0) { *loss_acc = 0ULL; *flag_cnt = 0; *fin_cnt = 0; }
        out[ESUM_OFF + threadIdx.x] = 0.f;             // 256 zeros
    }

    const float4* e4 = reinterpret_cast<const float4*>(emb + (size_t)k * CDIM + g * 8);
    float4 va = e4[0], vb = e4[1];                      // coalesced
    float f[8] = {va.x, va.y, va.z, va.w, vb.x, vb.y, vb.z, vb.w};

    unsigned fpk[4];
    float s = 0.f;
#pragma unroll
    for (int p = 0; p < 4; p++) {
        float v0 = f[2 * p], v1 = f[2 * p + 1];
        union { _Float16 h[2]; unsigned u; } pk;
        pk.h[0] = (_Float16)v0; pk.h[1] = (_Float16)v1;
        fpk[p] = pk.u;
        s = fmaf(v0, v0, s); s = fmaf(v1, v1, s);
    }
    Bpk16[(size_t)k * 16 + (g ^ (k & 15))] = make_uint4(fpk[0], fpk[1], fpk[2], fpk[3]);

    // emb passthrough (EMB_OFF is odd -> 4B-aligned scalar stores)
#pragma unroll
    for (int i = 0; i < 8; i++)
        out[EMB_OFF + (size_t)k * CDIM + g * 8 + i] = f[i];

    // ||e||^2 across the 16 granule-threads of this code (contiguous lanes)
    s += __shfl_xor(s, 1); s += __shfl_xor(s, 2);
    s += __shfl_xor(s, 4); s += __shfl_xor(s, 8);
    if (g == 0) esq[k] = s;
}

// ---- stage 1: fp16 single-pass scoring + fused emit (r14-proven shape) ------
__global__ __launch_bounds__(256, 4) void score_kernel(const float* __restrict__ in,
                                                       const uint4* __restrict__ Bpk,
                                                       const float* __restrict__ esq,
                                                       const float* __restrict__ emb,
                                                       float* __restrict__ out,
                                                       int* __restrict__ flag_list,
                                                       int* __restrict__ flag_cnt,
                                                       ull* __restrict__ key_ws,
                                                       float* __restrict__ xsq_ws,
                                                       ull* __restrict__ loss_acc) {
    __shared__ uint4 BB[3][TCODES * 16];     // 3 x 8 KB ring
    __shared__ int   i1L[128];
    __shared__ float xsqL[128];
    __shared__ ull   redL[16];

    const int tid = threadIdx.x;
    const int lane = tid & 63;
    const int w = tid >> 6;              // wave 0..3, owns rows w*32..w*32+31
    const int l15 = lane & 15;
    const int lg = lane >> 4;
    const int row0 = blockIdx.x * 128;
    const int b = row0 >> 15;
    const int sbase = (row0 & (SPATIAL - 1)) + w * 32;

#define STAGE(tt, bb)                                                     \
    do {                                                                  \
        const uint4* src_ = Bpk + (size_t)(tt) * 512;                     \
        _Pragma("unroll")                                                 \
        for (int i_ = 0; i_ < 2; i_++)                                    \
            gload16(src_ + i_ * 256 + tid, &BB[bb][i_ * 256 + tid]);      \
    } while (0)

    STAGE(0, 0);
    STAGE(1, 1);

    half8 Af[8];
    float xsq[2] = {0.f, 0.f};
    {
        const float* xb = in + (size_t)b * CDIM * SPATIAL;
#pragma unroll
        for (int kk = 0; kk < 4; kk++)
#pragma unroll
            for (int m = 0; m < 2; m++) {
                int srow = sbase + m * 16 + l15;
                union { unsigned u[4]; half8 h; } pk;
#pragma unroll
                for (int p = 0; p < 4; p++) {
                    int c0 = kk * 32 + lg * 8 + 2 * p;
                    float v0 = xb[(size_t)(c0 + 0) * SPATIAL + srow];
                    float v1 = xb[(size_t)(c0 + 1) * SPATIAL + srow];
                    union { _Float16 h[2]; unsigned u; } q;
                    q.h[0] = (_Float16)v0; q.h[1] = (_Float16)v1;
                    pk.u[p] = q.u;
                    xsq[m] = fmaf(v0, v0, xsq[m]);
                    xsq[m] = fmaf(v1, v1, xsq[m]);
                }
                Af[kk * 2 + m] = pk.h;
            }
    }
#pragma unroll
    for (int m = 0; m < 2; m++) {
        xsq[m] += __shfl_xor(xsq[m], 16);
        xsq[m] += __shfl_xor(xsq[m], 32);
    }
    if (lg == 0) {
        xsqL[w * 32 + l15] = xsq[0];
        xsqL[w * 32 + 16 + l15] = xsq[1];
    }

    float b1[8], b2[8];
    int i1[8];
#pragma unroll
    for (int i = 0; i < 8; i++) { b1[i] = FINF; b2[i] = FINF; i1[i] = 0; }

    for (int t = 0; t < NT; t++) {
        // wait own tile-t loads (keep tile t+1's 2 in flight); never vmcnt(0) mid-loop
        if (t == NT - 1) asm volatile("s_waitcnt vmcnt(0)" ::: "memory");
        else             asm volatile("s_waitcnt vmcnt(2)" ::: "memory");
        __builtin_amdgcn_s_barrier();
        if (t + 2 < NT) STAGE(t + 2, (t + 2) % 3);

        const half8* Bs = reinterpret_cast<const half8*>(BB[t % 3]);
        f32x4 acc[2][2];
#pragma unroll
        for (int m = 0; m < 2; m++)
#pragma unroll
            for (int n = 0; n < 2; n++) acc[m][n] = (f32x4){0.f, 0.f, 0.f, 0.f};

#pragma unroll
        for (int kk = 0; kk < 4; kk++) {
            int phys = (kk * 4 + lg) ^ l15;
            half8 bv[2];
#pragma unroll
            for (int n = 0; n < 2; n++) bv[n] = Bs[(n * 16 + l15) * 16 + phys];
#pragma unroll
            for (int m = 0; m < 2; m++)
#pragma unroll
                for (int n = 0; n < 2; n++)
                    acc[m][n] = __builtin_amdgcn_mfma_f32_16x16x32_f16(Af[kk * 2 + m], bv[n], acc[m][n], 0, 0, 0);
        }

#pragma unroll
        for (int n = 0; n < 2; n++) {
            int col = t * TCODES + n * 16 + l15;
            float ev = esq[col];
#pragma unroll
            for (int m = 0; m < 2; m++)
#pragma unroll
                for (int r = 0; r < 4; r++) {
                    float sv = fmaf(-2.f, acc[m][n][r], ev);
                    int slot = m * 4 + r;
                    bool c = sv < b1[slot];
                    b2[slot] = fminf(fmaxf(sv, b1[slot]), b2[slot]);
                    b1[slot] = fminf(sv, b1[slot]);
                    i1[slot] = c ? col : i1[slot];
                }
        }
    }
#undef STAGE

#pragma unroll
    for (int j = 1; j < 16; j <<= 1) {
#pragma unroll
        for (int slot = 0; slot < 8; slot++) {
            float ob1 = __shfl_xor(b1[slot], j);
            float ob2 = __shfl_xor(b2[slot], j);
            int   oi  = __shfl_xor(i1[slot], j);
            bool take = (ob1 < b1[slot]) || (ob1 == b1[slot] && oi < i1[slot]);
            float nb2 = fminf(fmaxf(b1[slot], ob1), fminf(b2[slot], ob2));
            b1[slot] = take ? ob1 : b1[slot];
            i1[slot] = take ? oi : i1[slot];
            b2[slot] = nb2;
        }
    }

    __syncthreads();   // xsqL visible across lanes; BB reads done

    if (l15 == 0) {
        ull lsum = 0;
#pragma unroll
        for (int m = 0; m < 2; m++)
#pragma unroll
            for (int r = 0; r < 4; r++) {
                int slot = m * 4 + r;
                int rl = w * 32 + m * 16 + lg * 4 + r;
                i1L[rl] = i1[slot];
                float cexp = b1[slot] + xsqL[rl];
                ull ci = (ull)llrintf(cexp * LSCALE);
                if (b2[slot] - b1[slot] < MARGIN1) {
                    int p = atomicAdd(flag_cnt, 1);
                    if (p < CAP1) {
                        flag_list[p] = row0 + rl;
                        key_ws[p] = ~0ULL;            // init for refine's atomicMin
                        xsq_ws[p] = xsqL[rl];         // exact ||x||^2 for loss
                        ci = 0;                       // refine adds exact loss
                    }
                }
                lsum += ci;
            }
        redL[w * 4 + lg] = lsum;
    }
    __syncthreads();
    if (tid == 0) {
        ull s = 0;
#pragma unroll
        for (int i = 0; i < 16; i++) s += redL[i];
        atomicAdd(loss_acc, s);
    }

    {
        const int rl = w * 32 + (lane & 31);
        const int row = row0 + rl;
        const int sp = (row0 & (SPATIAL - 1)) + rl;
        const int k = i1L[rl];
        const int chalf = lane >> 5;

        if (chalf == 0) out[IDX_OFF + row] = (float)k;
        const float4* ep = reinterpret_cast<const float4*>(emb + (size_t)k * CDIM + chalf * 64);
        float* qout = out + (size_t)b * CDIM * SPATIAL + (size_t)chalf * 64 * SPATIAL + sp;
#pragma unroll
        for (int i = 0; i < 16; i++) {
            float4 v = ep[i];
            qout[(size_t)(4 * i + 0) * SPATIAL] = v.x;
            qout[(size_t)(4 * i + 1) * SPATIAL] = v.y;
            qout[(size_t)(4 * i + 2) * SPATIAL] = v.z;
            qout[(size_t)(4 * i + 3) * SPATIAL] = v.w;
        }
    }
}

// ---- stage 2a: compact flagged x-rows (the ONLY scattered read, done once) --
__global__ __launch_bounds__(256) void xgather_kernel(const float* __restrict__ in,
                                                      const int* __restrict__ flag_list,
                                                      const int* __restrict__ flag_cnt,
                                                      float* __restrict__ xrow_ws) {
    int n1 = *flag_cnt; if (n1 > CAP1) n1 = CAP1;
    const int c = threadIdx.x & 127;            // channel
    const int fi = blockIdx.x * 2 + (threadIdx.x >> 7);
    if (fi >= n1) return;
    const int row = flag_list[fi];
    const int bb = row >> 15, sp = row & (SPATIAL - 1);
    xrow_ws[(size_t)fi * CDIM + c] = in[((size_t)bb * CDIM + c) * SPATIAL + sp];
}

// ---- stage 2b: exact fp32 scan over transposed codebook (coalesced) ---------
__global__ __launch_bounds__(256) void refine_scan_kernel(const float* __restrict__ xrow_ws,
                                                          const float* __restrict__ ecT,
                                                          const float* __restrict__ esq,
                                                          const int* __restrict__ flag_cnt,
                                                          ull* __restrict__ key_ws) {
    __shared__ float xL[RB_ROWS][132];   // padded

    int n1 = *flag_cnt; if (n1 > CAP1) n1 = CAP1;
    const int rb = blockIdx.x >> 3;            // rowblock
    const int chunk = blockIdx.x & 7;          // code chunk (128 codes)
    const int base = rb * RB_ROWS;
    if (base >= n1) return;

    const int t = threadIdx.x;
    const int row = t >> 4;                    // 0..15
    const int l = t & 15;

    // stage 16 compact x-rows into LDS — coalesced float4 reads (L2-hot)
    {
        const float4* src = reinterpret_cast<const float4*>(xrow_ws + (size_t)(base + row) * CDIM);
        float4* dst = reinterpret_cast<float4*>(&xL[row][0]);
        dst[l * 2] = src[l * 2];
        dst[l * 2 + 1] = src[l * 2 + 1];
    }
    __syncthreads();

    const float4* e4 = reinterpret_cast<const float4*>(ecT);
    const int cbase = chunk * 32 + l;          // float4 index within a channel row

    f32x4 accA = {0.f, 0.f, 0.f, 0.f};
    f32x4 accB = {0.f, 0.f, 0.f, 0.f};
#pragma unroll 8
    for (int c = 0; c < CDIM; c++) {
        float xx = xL[row][c];                 // 16-way broadcast, rows on distinct banks
        float4 va = e4[(size_t)c * 256 + cbase];         // lanes: 256B contiguous
        float4 vb = e4[(size_t)c * 256 + cbase + 16];
        accA[0] = fmaf(va.x, xx, accA[0]);
        accA[1] = fmaf(va.y, xx, accA[1]);
        accA[2] = fmaf(va.z, xx, accA[2]);
        accA[3] = fmaf(va.w, xx, accA[3]);
        accB[0] = fmaf(vb.x, xx, accB[0]);
        accB[1] = fmaf(vb.y, xx, accB[1]);
        accB[2] = fmaf(vb.z, xx, accB[2]);
        accB[3] = fmaf(vb.w, xx, accB[3]);
    }

    const int kA = chunk * 128 + 4 * l;        // codes kA..kA+3
    const int kB = kA + 64;                    // codes kB..kB+3
    ull key = ~0ULL;
#pragma unroll
    for (int j = 0; j < 4; j++) {
        float dA = fmaf(-2.f, accA[j], esq[kA + j]);
        ull cA = ((ull)ford(dA) << 32) | (unsigned)(kA + j);
        key = (cA < key) ? cA : key;
        float dB = fmaf(-2.f, accB[j], esq[kB + j]);
        ull cB = ((ull)ford(dB) << 32) | (unsigned)(kB + j);
        key = (cB < key) ? cB : key;
    }

    // reduce across the 16 lanes of this row (contiguous 16-group)
#pragma unroll
    for (int m = 1; m < 16; m <<= 1) {
        ull o = __shfl_xor(key, m);
        key = (o < key) ? o : key;
    }
    if (l == 0 && base + row < n1) atomicMin(&key_ws[base + row], key);
}

// ---- stage 2c: emit refined rows + fused finalize ---------------------------
// Emit: idx, exact loss; q-row only if idx flipped. One fence + counter per
// BLOCK (not per row); the last-finishing block writes the loss scalar.
__global__ __launch_bounds__(128) void refine_emit_kernel(const float* __restrict__ emb,
                                                          const int* __restrict__ flag_list,
                                                          const int* __restrict__ flag_cnt,
                                                          const ull* __restrict__ key_ws,
                                                          const float* __restrict__ xsq_ws,
                                                          float* __restrict__ out,
                                                          ull* __restrict__ loss_acc,
                                                          int* __restrict__ fin_cnt) {
    __shared__ int sOld;
    int n1 = *flag_cnt; if (n1 > CAP1) n1 = CAP1;
    const int t = threadIdx.x;

    for (int p = blockIdx.x; p < n1; p += gridDim.x) {
        const ull key = key_ws[p];
        const int idx = (int)(key & 0xFFFFFFFFu);
        const float d = finv((unsigned)(key >> 32));
        const int row = flag_list[p];
        const int bb = row >> 15, sp = row & (SPATIAL - 1);

        if (t == 0) sOld = (int)out[IDX_OFF + row];   // score's pick (this launch)
        __syncthreads();
        const int oldidx = sOld;

        if (t == 0) {
            atomicAdd(loss_acc, (ull)llrintf((d + xsq_ws[p]) * LSCALE));
            if (idx != oldidx) out[IDX_OFF + row] = (float)idx;
        }
        if (idx != oldidx)                             // rewrite q only on flip
            out[(size_t)bb * CDIM * SPATIAL + (size_t)t * SPATIAL + sp] =
                emb[(size_t)idx * CDIM + t];
        __syncthreads();                               // sOld reuse
    }

    // fused finalize: one fence + one atomic per block
    if (t == 0) {
        __threadfence();
        int old = atomicAdd(fin_cnt, 1);
        if (old == (int)gridDim.x - 1) {               // all blocks' loss adds visible
            ull s = *((volatile ull*)loss_acc);
            out[LOSS_OFF] = (float)(0.25 * ((double)s / (double)LSCALE) / (double)Q_SIZE);
        }
    }
}

extern "C" void kernel_launch(void* const* d_in, const int* in_sizes, int n_in,
                              void* d_out, int out_size, void* d_ws, size_t ws_size,
                              hipStream_t stream) {
    const float* in = (const float*)d_in[0];
    const float* emb = (const float*)d_in[1];
    float* out = (float*)d_out;

    float* esq = (float*)d_ws;                                  // 4096 f32 (16 KB)
    uint4* Bpk16 = (uint4*)(esq + 4096);                        // 16384 uint4 (256 KB)
    float* ecT = (float*)(Bpk16 + 16384);                       // 128*1024 f32 (512 KB)
    ull* key_ws = (ull*)(ecT + CDIM * KCODES);                  // CAP1 ull (96 KB)
    float* xsq_ws = (float*)(key_ws + CAP1);                    // CAP1 f32 (48 KB)
    float* xrow_ws = xsq_ws + CAP1;                             // CAP1*128 f32 (6 MB)
    ull* loss_acc = (ull*)(xrow_ws + (size_t)CAP1 * CDIM);      // 8 B
    int* flag_cnt = (int*)(loss_acc + 1);
    int* fin_cnt = flag_cnt + 1;
    int* flag_list = fin_cnt + 1;                               // CAP1 i32

    prep_kernel<<<128, 256, 0, stream>>>(emb, Bpk16, ecT, esq, out,
                                         loss_acc, flag_cnt, fin_cnt);
    score_kernel<<<NROWS / 128, 256, 0, stream>>>(in, Bpk16, esq, emb, out,
                                                  flag_list, flag_cnt,
                                                  key_ws, xsq_ws, loss_acc);
    xgather_kernel<<<CAP1 / 2, 256, 0, stream>>>(in, flag_list, flag_cnt, xrow_ws);
    refine_scan_kernel<<<(CAP1 / RB_ROWS) * NCHUNK, 256, 0, stream>>>(
        xrow_ws, ecT, esq, flag_cnt, key_ws);
    refine_emit_kernel<<<EMIT_BLOCKS, 128, 0, stream>>>(emb, flag_list, flag_cnt,
                                                        key_ws, xsq_ws, out,
                                                        loss_acc, fin_cnt);
}

// Round 18
// 134.707 us; speedup vs baseline: 1.2296x; 1.2296x over previous
//
#include <hip/hip_runtime.h>

// Problem geometry (fixed by the reference)
#define SPATIAL 32768            // D*H*W
#define NB 4
#define CDIM 128
#define KCODES 1024
#define NROWS (NB * SPATIAL)     // 131072

// Output layout in d_out (all float32, concatenated in return order)
#define Q_SIZE (NB * CDIM * SPATIAL)     // 16777216
#define LOSS_OFF Q_SIZE
#define IDX_OFF (Q_SIZE + 1)
#define ESUM_OFF (IDX_OFF + NROWS)
#define EMB_OFF (ESUM_OFF + 256)

#define TCODES 32                // codes per tile (score)
#define NT (KCODES / TCODES)     // 32 tiles
#define MARGIN1 0.06f            // fp16 1-pass gap margin (proven r5/r7/r10-r17)
#define CAP1 12288
#define NCHUNK 8                 // refine_scan code chunks (128 codes each)
#define RB_ROWS 16               // refine_scan rows per block
#define FINF 3.4e38f
#define LSCALE 1048576.0f        // 2^20 fixed-point for deterministic loss

typedef _Float16 half8 __attribute__((ext_vector_type(8)));
typedef float f32x4 __attribute__((ext_vector_type(4)));
typedef unsigned long long ull;

// monotone float<->uint map (total order; invertible)
static __device__ __forceinline__ unsigned ford(float f) {
    unsigned u = __float_as_uint(f);
    return (u >> 31) ? ~u : (u | 0x80000000u);
}
static __device__ __forceinline__ float finv(unsigned o) {
    unsigned u = (o & 0x80000000u) ? (o & 0x7FFFFFFFu) : ~o;
    return __uint_as_float(u);
}

// ---- prep (merged): blocks 0-63: emb -> fp16 granule-major tiles + ||e||^2
// + passthrough + inits; blocks 64-127: emb -> ecT transpose (for refine). ---
// Bpk16 layout: [tile][granule g (0..15)][code-in-tile cl (0..31)] of uint4
// (8 fp16 = channels g*8..g*8+7). A wave's fragment load (fixed kk,n) touches
// 4 contiguous 256B segments -> coalesced global reads, L1/L2-served.
__global__ __launch_bounds__(256) void prep_kernel(const float* __restrict__ emb,
                                                   uint4* __restrict__ Bpk16,
                                                   float* __restrict__ ecT,
                                                   float* __restrict__ esq,
                                                   float* __restrict__ out,
                                                   ull* __restrict__ loss_acc,
                                                   int* __restrict__ flag_cnt) {
    if (blockIdx.x >= 64) {
        // transpose: emb [k][c] -> ecT [c][k]
        const int k0 = (blockIdx.x - 64) * 16;
        const int l = threadIdx.x & 15;
        const int gi = threadIdx.x >> 4;
#pragma unroll
        for (int i = 0; i < 8; i++) {
            int c = gi * 8 + i;
            ecT[(size_t)c * KCODES + k0 + l] = emb[(size_t)(k0 + l) * CDIM + c];
        }
        return;
    }

    const int task = blockIdx.x * 256 + threadIdx.x;   // 16384 tasks
    const int k = task >> 4, g = task & 15;

    if (blockIdx.x == 0) {
        if (threadIdx.x == 0) { *loss_acc = 0ULL; *flag_cnt = 0; }
        out[ESUM_OFF + threadIdx.x] = 0.f;             // 256 zeros
    }

    const float4* e4 = reinterpret_cast<const float4*>(emb + (size_t)k * CDIM + g * 8);
    float4 va = e4[0], vb = e4[1];                      // coalesced
    float f[8] = {va.x, va.y, va.z, va.w, vb.x, vb.y, vb.z, vb.w};

    unsigned fpk[4];
    float s = 0.f;
#pragma unroll
    for (int p = 0; p < 4; p++) {
        float v0 = f[2 * p], v1 = f[2 * p + 1];
        union { _Float16 h[2]; unsigned u; } pk;
        pk.h[0] = (_Float16)v0; pk.h[1] = (_Float16)v1;
        fpk[p] = pk.u;
        s = fmaf(v0, v0, s); s = fmaf(v1, v1, s);
    }
    // granule-major: [t][g][cl]
    Bpk16[(size_t)(k >> 5) * 512 + (size_t)g * 32 + (k & 31)] =
        make_uint4(fpk[0], fpk[1], fpk[2], fpk[3]);

    // emb passthrough (EMB_OFF is odd -> 4B-aligned scalar stores)
#pragma unroll
    for (int i = 0; i < 8; i++)
        out[EMB_OFF + (size_t)k * CDIM + g * 8 + i] = f[i];

    // ||e||^2 across the 16 granule-threads of this code (contiguous lanes)
    s += __shfl_xor(s, 1); s += __shfl_xor(s, 2);
    s += __shfl_xor(s, 4); s += __shfl_xor(s, 8);
    if (g == 0) esq[k] = s;
}

// ---- stage 1: fp16 single-pass scoring + fused emit, B direct from L1/L2 ----
// No LDS staging, no barriers, no lockstep: the 8 KB tile is L1-resident and
// L2-shared across all blocks; waves run free and the compiler pipelines the
// 8 independent fragment loads per tile against MFMA + min-tracking.
__global__ __launch_bounds__(256, 4) void score_kernel(const float* __restrict__ in,
                                                       const uint4* __restrict__ Bpk,
                                                       const float* __restrict__ esq,
                                                       const float* __restrict__ emb,
                                                       float* __restrict__ out,
                                                       int* __restrict__ flag_list,
                                                       int* __restrict__ flag_cnt,
                                                       ull* __restrict__ key_ws,
                                                       float* __restrict__ xsq_ws,
                                                       ull* __restrict__ loss_acc) {
    __shared__ int   i1L[128];
    __shared__ float xsqL[128];
    __shared__ ull   redL[16];

    const int tid = threadIdx.x;
    const int lane = tid & 63;
    const int w = tid >> 6;              // wave 0..3, owns rows w*32..w*32+31
    const int l15 = lane & 15;
    const int lg = lane >> 4;
    const int row0 = blockIdx.x * 128;
    const int b = row0 >> 15;
    const int sbase = (row0 & (SPATIAL - 1)) + w * 32;

    half8 Af[8];
    float xsq[2] = {0.f, 0.f};
    {
        const float* xb = in + (size_t)b * CDIM * SPATIAL;
#pragma unroll
        for (int kk = 0; kk < 4; kk++)
#pragma unroll
            for (int m = 0; m < 2; m++) {
                int srow = sbase + m * 16 + l15;
                union { unsigned u[4]; half8 h; } pk;
#pragma unroll
                for (int p = 0; p < 4; p++) {
                    int c0 = kk * 32 + lg * 8 + 2 * p;
                    float v0 = xb[(size_t)(c0 + 0) * SPATIAL + srow];
                    float v1 = xb[(size_t)(c0 + 1) * SPATIAL + srow];
                    union { _Float16 h[2]; unsigned u; } q;
                    q.h[0] = (_Float16)v0; q.h[1] = (_Float16)v1;
                    pk.u[p] = q.u;
                    xsq[m] = fmaf(v0, v0, xsq[m]);
                    xsq[m] = fmaf(v1, v1, xsq[m]);
                }
                Af[kk * 2 + m] = pk.h;
            }
    }
#pragma unroll
    for (int m = 0; m < 2; m++) {
        xsq[m] += __shfl_xor(xsq[m], 16);
        xsq[m] += __shfl_xor(xsq[m], 32);
    }
    if (lg == 0) {
        xsqL[w * 32 + l15] = xsq[0];
        xsqL[w * 32 + 16 + l15] = xsq[1];
    }

    float b1[8], b2[8];
    int i1[8];
#pragma unroll
    for (int i = 0; i < 8; i++) { b1[i] = FINF; b2[i] = FINF; i1[i] = 0; }

    const half8* Bg = reinterpret_cast<const half8*>(Bpk);
    for (int t = 0; t < NT; t++) {
        const half8* Bs = Bg + (size_t)t * 512;   // this tile (8 KB, L1/L2-hot)
        f32x4 acc[2][2];
#pragma unroll
        for (int m = 0; m < 2; m++)
#pragma unroll
            for (int n = 0; n < 2; n++) acc[m][n] = (f32x4){0.f, 0.f, 0.f, 0.f};

#pragma unroll
        for (int kk = 0; kk < 4; kk++) {
            half8 bv[2];
#pragma unroll
            for (int n = 0; n < 2; n++)
                bv[n] = Bs[(kk * 4 + lg) * 32 + n * 16 + l15];   // 4x256B segments
#pragma unroll
            for (int m = 0; m < 2; m++)
#pragma unroll
                for (int n = 0; n < 2; n++)
                    acc[m][n] = __builtin_amdgcn_mfma_f32_16x16x32_f16(Af[kk * 2 + m], bv[n], acc[m][n], 0, 0, 0);
        }

#pragma unroll
        for (int n = 0; n < 2; n++) {
            int col = t * TCODES + n * 16 + l15;
            float ev = esq[col];
#pragma unroll
            for (int m = 0; m < 2; m++)
#pragma unroll
                for (int r = 0; r < 4; r++) {
                    float sv = fmaf(-2.f, acc[m][n][r], ev);
                    int slot = m * 4 + r;
                    bool c = sv < b1[slot];
                    b2[slot] = fminf(fmaxf(sv, b1[slot]), b2[slot]);
                    b1[slot] = fminf(sv, b1[slot]);
                    i1[slot] = c ? col : i1[slot];
                }
        }
    }

#pragma unroll
    for (int j = 1; j < 16; j <<= 1) {
#pragma unroll
        for (int slot = 0; slot < 8; slot++) {
            float ob1 = __shfl_xor(b1[slot], j);
            float ob2 = __shfl_xor(b2[slot], j);
            int   oi  = __shfl_xor(i1[slot], j);
            bool take = (ob1 < b1[slot]) || (ob1 == b1[slot] && oi < i1[slot]);
            float nb2 = fminf(fmaxf(b1[slot], ob1), fminf(b2[slot], ob2));
            b1[slot] = take ? ob1 : b1[slot];
            i1[slot] = take ? oi : i1[slot];
            b2[slot] = nb2;
        }
    }

    __syncthreads();   // xsqL visible across lanes

    if (l15 == 0) {
        ull lsum = 0;
#pragma unroll
        for (int m = 0; m < 2; m++)
#pragma unroll
            for (int r = 0; r < 4; r++) {
                int slot = m * 4 + r;
                int rl = w * 32 + m * 16 + lg * 4 + r;
                i1L[rl] = i1[slot];
                float cexp = b1[slot] + xsqL[rl];
                ull ci = (ull)llrintf(cexp * LSCALE);
                if (b2[slot] - b1[slot] < MARGIN1) {
                    int p = atomicAdd(flag_cnt, 1);
                    if (p < CAP1) {
                        flag_list[p] = row0 + rl;
                        key_ws[p] = ~0ULL;            // init for refine's atomicMin
                        xsq_ws[p] = xsqL[rl];         // exact ||x||^2 for loss
                        ci = 0;                       // refine adds exact loss
                    }
                }
                lsum += ci;
            }
        redL[w * 4 + lg] = lsum;
    }
    __syncthreads();
    if (tid == 0) {
        ull s = 0;
#pragma unroll
        for (int i = 0; i < 16; i++) s += redL[i];
        atomicAdd(loss_acc, s);
    }

    {
        const int rl = w * 32 + (lane & 31);
        const int row = row0 + rl;
        const int sp = (row0 & (SPATIAL - 1)) + rl;
        const int k = i1L[rl];
        const int chalf = lane >> 5;

        if (chalf == 0) out[IDX_OFF + row] = (float)k;
        const float4* ep = reinterpret_cast<const float4*>(emb + (size_t)k * CDIM + chalf * 64);
        float* qout = out + (size_t)b * CDIM * SPATIAL + (size_t)chalf * 64 * SPATIAL + sp;
#pragma unroll
        for (int i = 0; i < 16; i++) {
            float4 v = ep[i];
            qout[(size_t)(4 * i + 0) * SPATIAL] = v.x;
            qout[(size_t)(4 * i + 1) * SPATIAL] = v.y;
            qout[(size_t)(4 * i + 2) * SPATIAL] = v.z;
            qout[(size_t)(4 * i + 3) * SPATIAL] = v.w;
        }
    }
}

// ---- stage 2a: compact flagged x-rows (the ONLY scattered read, done once) --
__global__ __launch_bounds__(256) void xgather_kernel(const float* __restrict__ in,
                                                      const int* __restrict__ flag_list,
                                                      const int* __restrict__ flag_cnt,
                                                      float* __restrict__ xrow_ws) {
    int n1 = *flag_cnt; if (n1 > CAP1) n1 = CAP1;
    const int c = threadIdx.x & 127;            // channel
    const int fi = blockIdx.x * 2 + (threadIdx.x >> 7);
    if (fi >= n1) return;
    const int row = flag_list[fi];
    const int bb = row >> 15, sp = row & (SPATIAL - 1);
    xrow_ws[(size_t)fi * CDIM + c] = in[((size_t)bb * CDIM + c) * SPATIAL + sp];
}

// ---- stage 2b: exact fp32 scan over transposed codebook (coalesced) ---------
__global__ __launch_bounds__(256) void refine_scan_kernel(const float* __restrict__ xrow_ws,
                                                          const float* __restrict__ ecT,
                                                          const float* __restrict__ esq,
                                                          const int* __restrict__ flag_cnt,
                                                          ull* __restrict__ key_ws) {
    __shared__ float xL[RB_ROWS][132];   // padded

    int n1 = *flag_cnt; if (n1 > CAP1) n1 = CAP1;
    const int rb = blockIdx.x >> 3;            // rowblock
    const int chunk = blockIdx.x & 7;          // code chunk (128 codes)
    const int base = rb * RB_ROWS;
    if (base >= n1) return;

    const int t = threadIdx.x;
    const int row = t >> 4;                    // 0..15
    const int l = t & 15;

    // stage 16 compact x-rows into LDS — coalesced float4 reads (L2-hot)
    {
        const float4* src = reinterpret_cast<const float4*>(xrow_ws + (size_t)(base + row) * CDIM);
        float4* dst = reinterpret_cast<float4*>(&xL[row][0]);
        dst[l * 2] = src[l * 2];
        dst[l * 2 + 1] = src[l * 2 + 1];
    }
    __syncthreads();

    const float4* e4 = reinterpret_cast<const float4*>(ecT);
    const int cbase = chunk * 32 + l;          // float4 index within a channel row

    f32x4 accA = {0.f, 0.f, 0.f, 0.f};
    f32x4 accB = {0.f, 0.f, 0.f, 0.f};
#pragma unroll 8
    for (int c = 0; c < CDIM; c++) {
        float xx = xL[row][c];                 // 16-way broadcast, rows on distinct banks
        float4 va = e4[(size_t)c * 256 + cbase];         // lanes: 256B contiguous
        float4 vb = e4[(size_t)c * 256 + cbase + 16];
        accA[0] = fmaf(va.x, xx, accA[0]);
        accA[1] = fmaf(va.y, xx, accA[1]);
        accA[2] = fmaf(va.z, xx, accA[2]);
        accA[3] = fmaf(va.w, xx, accA[3]);
        accB[0] = fmaf(vb.x, xx, accB[0]);
        accB[1] = fmaf(vb.y, xx, accB[1]);
        accB[2] = fmaf(vb.z, xx, accB[2]);
        accB[3] = fmaf(vb.w, xx, accB[3]);
    }

    const int kA = chunk * 128 + 4 * l;        // codes kA..kA+3
    const int kB = kA + 64;                    // codes kB..kB+3
    ull key = ~0ULL;
#pragma unroll
    for (int j = 0; j < 4; j++) {
        float dA = fmaf(-2.f, accA[j], esq[kA + j]);
        ull cA = ((ull)ford(dA) << 32) | (unsigned)(kA + j);
        key = (cA < key) ? cA : key;
        float dB = fmaf(-2.f, accB[j], esq[kB + j]);
        ull cB = ((ull)ford(dB) << 32) | (unsigned)(kB + j);
        key = (cB < key) ? cB : key;
    }

    // reduce across the 16 lanes of this row (contiguous 16-group)
#pragma unroll
    for (int m = 1; m < 16; m <<= 1) {
        ull o = __shfl_xor(key, m);
        key = (o < key) ? o : key;
    }
    if (l == 0 && base + row < n1) atomicMin(&key_ws[base + row], key);
}

// ---- stage 2c: emit refined rows: idx, exact loss; q-row only if idx flipped -
__global__ __launch_bounds__(128) void refine_emit_kernel(const float* __restrict__ emb,
                                                          const int* __restrict__ flag_list,
                                                          const int* __restrict__ flag_cnt,
                                                          const ull* __restrict__ key_ws,
                                                          const float* __restrict__ xsq_ws,
                                                          float* __restrict__ out,
                                                          ull* __restrict__ loss_acc) {
    __shared__ int sOld;
    int n1 = *flag_cnt; if (n1 > CAP1) n1 = CAP1;
    const int t = threadIdx.x;

    for (int p = blockIdx.x; p < n1; p += gridDim.x) {
        const ull key = key_ws[p];
        const int idx = (int)(key & 0xFFFFFFFFu);
        const float d = finv((unsigned)(key >> 32));
        const int row = flag_list[p];
        const int bb = row >> 15, sp = row & (SPATIAL - 1);

        if (t == 0) sOld = (int)out[IDX_OFF + row];   // score's pick (this launch)
        __syncthreads();
        const int oldidx = sOld;

        if (t == 0) {
            atomicAdd(loss_acc, (ull)llrintf((d + xsq_ws[p]) * LSCALE));
            if (idx != oldidx) out[IDX_OFF + row] = (float)idx;
        }
        if (idx != oldidx)                             // rewrite q only on flip
            out[(size_t)bb * CDIM * SPATIAL + (size_t)t * SPATIAL + sp] =
                emb[(size_t)idx * CDIM + t];
        __syncthreads();                               // sOld reuse
    }
}

// ---- finalize: fixed-point -> float loss ------------------------------------
__global__ void finalize_kernel(const ull* __restrict__ loss_acc,
                                float* __restrict__ out) {
    double s = (double)*loss_acc / (double)LSCALE;
    out[LOSS_OFF] = (float)(0.25 * s / (double)Q_SIZE);
}

extern "C" void kernel_launch(void* const* d_in, const int* in_sizes, int n_in,
                              void* d_out, int out_size, void* d_ws, size_t ws_size,
                              hipStream_t stream) {
    const float* in = (const float*)d_in[0];
    const float* emb = (const float*)d_in[1];
    float* out = (float*)d_out;

    float* esq = (float*)d_ws;                                  // 4096 f32 (16 KB)
    uint4* Bpk16 = (uint4*)(esq + 4096);                        // 16384 uint4 (256 KB)
    float* ecT = (float*)(Bpk16 + 16384);                       // 128*1024 f32 (512 KB)
    ull* key_ws = (ull*)(ecT + CDIM * KCODES);                  // CAP1 ull (96 KB)
    float* xsq_ws = (float*)(key_ws + CAP1);                    // CAP1 f32 (48 KB)
    float* xrow_ws = xsq_ws + CAP1;                             // CAP1*128 f32 (6 MB)
    ull* loss_acc = (ull*)(xrow_ws + (size_t)CAP1 * CDIM);      // 8 B
    int* flag_cnt = (int*)(loss_acc + 1);
    int* flag_list = flag_cnt + 1;                              // CAP1 i32

    prep_kernel<<<128, 256, 0, stream>>>(emb, Bpk16, ecT, esq, out,
                                         loss_acc, flag_cnt);
    score_kernel<<<NROWS / 128, 256, 0, stream>>>(in, Bpk16, esq, emb, out,
                                                  flag_list, flag_cnt,
                                                  key_ws, xsq_ws, loss_acc);
    xgather_kernel<<<CAP1 / 2, 256, 0, stream>>>(in, flag_list, flag_cnt, xrow_ws);
    refine_scan_kernel<<<(CAP1 / RB_ROWS) * NCHUNK, 256, 0, stream>>>(
        xrow_ws, ecT, esq, flag_cnt, key_ws);
    refine_emit_kernel<<<2048, 128, 0, stream>>>(emb, flag_list, flag_cnt,
                                                 key_ws, xsq_ws, out, loss_acc);
    finalize_kernel<<<1, 1, 0, stream>>>(loss_acc, out);
}

// Round 19
// 132.055 us; speedup vs baseline: 1.2543x; 1.0201x over previous
//
#include <hip/hip_runtime.h>

// Problem geometry (fixed by the reference)
#define SPATIAL 32768            // D*H*W
#define NB 4
#define CDIM 128
#define KCODES 1024
#define NROWS (NB * SPATIAL)     // 131072

// Output layout in d_out (all float32, concatenated in return order)
#define Q_SIZE (NB * CDIM * SPATIAL)     // 16777216
#define LOSS_OFF Q_SIZE
#define IDX_OFF (Q_SIZE + 1)
#define ESUM_OFF (IDX_OFF + NROWS)
#define EMB_OFF (ESUM_OFF + 256)

#define TCODES 32                // codes per tile (score)
#define NT (KCODES / TCODES)     // 32 tiles
#define MARGIN1 0.06f            // fp16 1-pass gap margin (proven r5-r18)
#define CAP1 12288
#define NCHUNK 8                 // refine_scan code chunks (128 codes each)
#define RB_ROWS 16               // refine_scan rows per block
#define FINF 3.4e38f
#define LSCALE 1048576.0f        // 2^20 fixed-point for deterministic loss

typedef _Float16 half8 __attribute__((ext_vector_type(8)));
typedef float f32x4 __attribute__((ext_vector_type(4)));
typedef unsigned long long ull;

static __device__ __forceinline__ void gload16(const uint4* g, uint4* l) {
    __builtin_amdgcn_global_load_lds(
        (const __attribute__((address_space(1))) unsigned int*)g,
        (__attribute__((address_space(3))) unsigned int*)l, 16, 0, 0);
}

// monotone float<->uint map (total order; invertible)
static __device__ __forceinline__ unsigned ford(float f) {
    unsigned u = __float_as_uint(f);
    return (u >> 31) ? ~u : (u | 0x80000000u);
}
static __device__ __forceinline__ float finv(unsigned o) {
    unsigned u = (o & 0x80000000u) ? (o & 0x7FFFFFFFu) : ~o;
    return __uint_as_float(u);
}

// ---- prep (merged): blocks 0-63: emb -> fp16 tiles + ||e||^2 + passthrough
// + inits; blocks 64-127: emb -> ecT transpose (channel-major, for refine). --
__global__ __launch_bounds__(256) void prep_kernel(const float* __restrict__ emb,
                                                   uint4* __restrict__ Bpk16,
                                                   float* __restrict__ ecT,
                                                   float* __restrict__ esq,
                                                   float* __restrict__ out,
                                                   ull* __restrict__ loss_acc,
                                                   int* __restrict__ flag_cnt) {
    if (blockIdx.x >= 64) {
        // transpose: emb [k][c] -> ecT [c][k]
        const int k0 = (blockIdx.x - 64) * 16;
        const int l = threadIdx.x & 15;
        const int gi = threadIdx.x >> 4;
#pragma unroll
        for (int i = 0; i < 8; i++) {
            int c = gi * 8 + i;
            ecT[(size_t)c * KCODES + k0 + l] = emb[(size_t)(k0 + l) * CDIM + c];
        }
        return;
    }

    const int task = blockIdx.x * 256 + threadIdx.x;   // 16384 tasks
    const int k = task >> 4, g = task & 15;

    if (blockIdx.x == 0) {
        if (threadIdx.x == 0) { *loss_acc = 0ULL; *flag_cnt = 0; }
        out[ESUM_OFF + threadIdx.x] = 0.f;             // 256 zeros
    }

    const float4* e4 = reinterpret_cast<const float4*>(emb + (size_t)k * CDIM + g * 8);
    float4 va = e4[0], vb = e4[1];                      // coalesced
    float f[8] = {va.x, va.y, va.z, va.w, vb.x, vb.y, vb.z, vb.w};

    unsigned fpk[4];
    float s = 0.f;
#pragma unroll
    for (int p = 0; p < 4; p++) {
        float v0 = f[2 * p], v1 = f[2 * p + 1];
        union { _Float16 h[2]; unsigned u; } pk;
        pk.h[0] = (_Float16)v0; pk.h[1] = (_Float16)v1;
        fpk[p] = pk.u;
        s = fmaf(v0, v0, s); s = fmaf(v1, v1, s);
    }
    Bpk16[(size_t)k * 16 + (g ^ (k & 15))] = make_uint4(fpk[0], fpk[1], fpk[2], fpk[3]);

    // emb passthrough (EMB_OFF is odd -> 4B-aligned scalar stores)
#pragma unroll
    for (int i = 0; i < 8; i++)
        out[EMB_OFF + (size_t)k * CDIM + g * 8 + i] = f[i];

    // ||e||^2 across the 16 granule-threads of this code (contiguous lanes)
    s += __shfl_xor(s, 1); s += __shfl_xor(s, 2);
    s += __shfl_xor(s, 4); s += __shfl_xor(s, 8);
    if (g == 0) esq[k] = s;
}

// ---- stage 1: fp16 single-pass scoring + fused emit; 256 thr / 128 rows -----
// Small 8 KB tiles: 3-ring = 24 KB LDS -> ~26 KB total -> 6 blocks/CU capacity;
// grid 1024 -> 4 resident blocks/CU (16 waves): barrier stalls hide across blocks.
__global__ __launch_bounds__(256, 4) void score_kernel(const float* __restrict__ in,
                                                       const uint4* __restrict__ Bpk,
                                                       const float* __restrict__ esq,
                                                       const float* __restrict__ emb,
                                                       float* __restrict__ out,
                                                       int* __restrict__ flag_list,
                                                       int* __restrict__ flag_cnt,
                                                       ull* __restrict__ key_ws,
                                                       float* __restrict__ xsq_ws,
                                                       ull* __restrict__ loss_acc) {
    __shared__ uint4 BB[3][TCODES * 16];     // 3 x 8 KB ring
    __shared__ int   i1L[128];
    __shared__ float xsqL[128];
    __shared__ ull   redL[16];

    const int tid = threadIdx.x;
    const int lane = tid & 63;
    const int w = tid >> 6;              // wave 0..3, owns rows w*32..w*32+31
    const int l15 = lane & 15;
    const int lg = lane >> 4;
    const int row0 = blockIdx.x * 128;
    const int b = row0 >> 15;
    const int sbase = (row0 & (SPATIAL - 1)) + w * 32;

#define STAGE(tt, bb)                                                     \
    do {                                                                  \
        const uint4* src_ = Bpk + (size_t)(tt) * 512;                     \
        _Pragma("unroll")                                                 \
        for (int i_ = 0; i_ < 2; i_++)                                    \
            gload16(src_ + i_ * 256 + tid, &BB[bb][i_ * 256 + tid]);      \
    } while (0)

    STAGE(0, 0);
    STAGE(1, 1);

    half8 Af[8];
    float xsq[2] = {0.f, 0.f};
    {
        const float* xb = in + (size_t)b * CDIM * SPATIAL;
#pragma unroll
        for (int kk = 0; kk < 4; kk++)
#pragma unroll
            for (int m = 0; m < 2; m++) {
                int srow = sbase + m * 16 + l15;
                union { unsigned u[4]; half8 h; } pk;
#pragma unroll
                for (int p = 0; p < 4; p++) {
                    int c0 = kk * 32 + lg * 8 + 2 * p;
                    float v0 = xb[(size_t)(c0 + 0) * SPATIAL + srow];
                    float v1 = xb[(size_t)(c0 + 1) * SPATIAL + srow];
                    union { _Float16 h[2]; unsigned u; } q;
                    q.h[0] = (_Float16)v0; q.h[1] = (_Float16)v1;
                    pk.u[p] = q.u;
                    xsq[m] = fmaf(v0, v0, xsq[m]);
                    xsq[m] = fmaf(v1, v1, xsq[m]);
                }
                Af[kk * 2 + m] = pk.h;
            }
    }
#pragma unroll
    for (int m = 0; m < 2; m++) {
        xsq[m] += __shfl_xor(xsq[m], 16);
        xsq[m] += __shfl_xor(xsq[m], 32);
    }
    if (lg == 0) {
        xsqL[w * 32 + l15] = xsq[0];
        xsqL[w * 32 + 16 + l15] = xsq[1];
    }

    float b1[8], b2[8];
    int i1[8];
#pragma unroll
    for (int i = 0; i < 8; i++) { b1[i] = FINF; b2[i] = FINF; i1[i] = 0; }

    for (int t = 0; t < NT; t++) {
        // wait own tile-t loads (keep tile t+1's 2 in flight); never vmcnt(0) mid-loop
        if (t == NT - 1) asm volatile("s_waitcnt vmcnt(0)" ::: "memory");
        else             asm volatile("s_waitcnt vmcnt(2)" ::: "memory");
        __builtin_amdgcn_s_barrier();
        if (t + 2 < NT) STAGE(t + 2, (t + 2) % 3);

        const half8* Bs = reinterpret_cast<const half8*>(BB[t % 3]);
        f32x4 acc[2][2];
#pragma unroll
        for (int m = 0; m < 2; m++)
#pragma unroll
            for (int n = 0; n < 2; n++) acc[m][n] = (f32x4){0.f, 0.f, 0.f, 0.f};

#pragma unroll
        for (int kk = 0; kk < 4; kk++) {
            int phys = (kk * 4 + lg) ^ l15;
            half8 bv[2];
#pragma unroll
            for (int n = 0; n < 2; n++) bv[n] = Bs[(n * 16 + l15) * 16 + phys];
#pragma unroll
            for (int m = 0; m < 2; m++)
#pragma unroll
                for (int n = 0; n < 2; n++)
                    acc[m][n] = __builtin_amdgcn_mfma_f32_16x16x32_f16(Af[kk * 2 + m], bv[n], acc[m][n], 0, 0, 0);
        }

#pragma unroll
        for (int n = 0; n < 2; n++) {
            int col = t * TCODES + n * 16 + l15;
            float ev = esq[col];
#pragma unroll
            for (int m = 0; m < 2; m++)
#pragma unroll
                for (int r = 0; r < 4; r++) {
                    float sv = fmaf(-2.f, acc[m][n][r], ev);
                    int slot = m * 4 + r;
                    bool c = sv < b1[slot];
                    b2[slot] = fminf(fmaxf(sv, b1[slot]), b2[slot]);
                    b1[slot] = fminf(sv, b1[slot]);
                    i1[slot] = c ? col : i1[slot];
                }
        }
    }
#undef STAGE

#pragma unroll
    for (int j = 1; j < 16; j <<= 1) {
#pragma unroll
        for (int slot = 0; slot < 8; slot++) {
            float ob1 = __shfl_xor(b1[slot], j);
            float ob2 = __shfl_xor(b2[slot], j);
            int   oi  = __shfl_xor(i1[slot], j);
            bool take = (ob1 < b1[slot]) || (ob1 == b1[slot] && oi < i1[slot]);
            float nb2 = fminf(fmaxf(b1[slot], ob1), fminf(b2[slot], ob2));
            b1[slot] = take ? ob1 : b1[slot];
            i1[slot] = take ? oi : i1[slot];
            b2[slot] = nb2;
        }
    }

    __syncthreads();   // xsqL visible across lanes; BB reads done

    if (l15 == 0) {
        ull lsum = 0;
#pragma unroll
        for (int m = 0; m < 2; m++)
#pragma unroll
            for (int r = 0; r < 4; r++) {
                int slot = m * 4 + r;
                int rl = w * 32 + m * 16 + lg * 4 + r;
                i1L[rl] = i1[slot];
                float cexp = b1[slot] + xsqL[rl];
                ull ci = (ull)llrintf(cexp * LSCALE);
                if (b2[slot] - b1[slot] < MARGIN1) {
                    int p = atomicAdd(flag_cnt, 1);
                    if (p < CAP1) {
                        flag_list[p] = row0 + rl;
                        key_ws[p] = ~0ULL;            // init for refine's atomicMin
                        xsq_ws[p] = xsqL[rl];         // exact ||x||^2 for loss
                        ci = 0;                       // refine adds exact loss
                    }
                }
                lsum += ci;
            }
        redL[w * 4 + lg] = lsum;
    }
    __syncthreads();
    if (tid == 0) {
        ull s = 0;
#pragma unroll
        for (int i = 0; i < 16; i++) s += redL[i];
        atomicAdd(loss_acc, s);
    }

    {
        const int rl = w * 32 + (lane & 31);
        const int row = row0 + rl;
        const int sp = (row0 & (SPATIAL - 1)) + rl;
        const int k = i1L[rl];
        const int chalf = lane >> 5;

        if (chalf == 0) out[IDX_OFF + row] = (float)k;
        const float4* ep = reinterpret_cast<const float4*>(emb + (size_t)k * CDIM + chalf * 64);
        float* qout = out + (size_t)b * CDIM * SPATIAL + (size_t)chalf * 64 * SPATIAL + sp;
#pragma unroll
        for (int i = 0; i < 16; i++) {
            float4 v = ep[i];
            qout[(size_t)(4 * i + 0) * SPATIAL] = v.x;
            qout[(size_t)(4 * i + 1) * SPATIAL] = v.y;
            qout[(size_t)(4 * i + 2) * SPATIAL] = v.z;
            qout[(size_t)(4 * i + 3) * SPATIAL] = v.w;
        }
    }
}

// ---- stage 2a: compact flagged x-rows (the ONLY scattered read, done once) --
__global__ __launch_bounds__(256) void xgather_kernel(const float* __restrict__ in,
                                                      const int* __restrict__ flag_list,
                                                      const int* __restrict__ flag_cnt,
                                                      float* __restrict__ xrow_ws) {
    int n1 = *flag_cnt; if (n1 > CAP1) n1 = CAP1;
    const int c = threadIdx.x & 127;            // channel
    const int fi = blockIdx.x * 2 + (threadIdx.x >> 7);
    if (fi >= n1) return;
    const int row = flag_list[fi];
    const int bb = row >> 15, sp = row & (SPATIAL - 1);
    xrow_ws[(size_t)fi * CDIM + c] = in[((size_t)bb * CDIM + c) * SPATIAL + sp];
}

// ---- stage 2b: exact fp32 scan over transposed codebook (coalesced) ---------
__global__ __launch_bounds__(256) void refine_scan_kernel(const float* __restrict__ xrow_ws,
                                                          const float* __restrict__ ecT,
                                                          const float* __restrict__ esq,
                                                          const int* __restrict__ flag_cnt,
                                                          ull* __restrict__ key_ws) {
    __shared__ float xL[RB_ROWS][132];   // padded

    int n1 = *flag_cnt; if (n1 > CAP1) n1 = CAP1;
    const int rb = blockIdx.x >> 3;            // rowblock
    const int chunk = blockIdx.x & 7;          // code chunk (128 codes)
    const int base = rb * RB_ROWS;
    if (base >= n1) return;

    const int t = threadIdx.x;
    const int row = t >> 4;                    // 0..15
    const int l = t & 15;

    // stage 16 compact x-rows into LDS — coalesced float4 reads (L2-hot)
    {
        const float4* src = reinterpret_cast<const float4*>(xrow_ws + (size_t)(base + row) * CDIM);
        float4* dst = reinterpret_cast<float4*>(&xL[row][0]);
        dst[l * 2] = src[l * 2];
        dst[l * 2 + 1] = src[l * 2 + 1];
    }
    __syncthreads();

    const float4* e4 = reinterpret_cast<const float4*>(ecT);
    const int cbase = chunk * 32 + l;          // float4 index within a channel row

    f32x4 accA = {0.f, 0.f, 0.f, 0.f};
    f32x4 accB = {0.f, 0.f, 0.f, 0.f};
#pragma unroll 8
    for (int c = 0; c < CDIM; c++) {
        float xx = xL[row][c];                 // 16-way broadcast, rows on distinct banks
        float4 va = e4[(size_t)c * 256 + cbase];         // lanes: 256B contiguous
        float4 vb = e4[(size_t)c * 256 + cbase + 16];
        accA[0] = fmaf(va.x, xx, accA[0]);
        accA[1] = fmaf(va.y, xx, accA[1]);
        accA[2] = fmaf(va.z, xx, accA[2]);
        accA[3] = fmaf(va.w, xx, accA[3]);
        accB[0] = fmaf(vb.x, xx, accB[0]);
        accB[1] = fmaf(vb.y, xx, accB[1]);
        accB[2] = fmaf(vb.z, xx, accB[2]);
        accB[3] = fmaf(vb.w, xx, accB[3]);
    }

    const int kA = chunk * 128 + 4 * l;        // codes kA..kA+3
    const int kB = kA + 64;                    // codes kB..kB+3
    ull key = ~0ULL;
#pragma unroll
    for (int j = 0; j < 4; j++) {
        float dA = fmaf(-2.f, accA[j], esq[kA + j]);
        ull cA = ((ull)ford(dA) << 32) | (unsigned)(kA + j);
        key = (cA < key) ? cA : key;
        float dB = fmaf(-2.f, accB[j], esq[kB + j]);
        ull cB = ((ull)ford(dB) << 32) | (unsigned)(kB + j);
        key = (cB < key) ? cB : key;
    }

    // reduce across the 16 lanes of this row (contiguous 16-group)
#pragma unroll
    for (int m = 1; m < 16; m <<= 1) {
        ull o = __shfl_xor(key, m);
        key = (o < key) ? o : key;
    }
    if (l == 0 && base + row < n1) atomicMin(&key_ws[base + row], key);
}

// ---- stage 2c: emit refined rows: idx, exact loss; q-row only if idx flipped -
__global__ __launch_bounds__(128) void refine_emit_kernel(const float* __restrict__ emb,
                                                          const int* __restrict__ flag_list,
                                                          const int* __restrict__ flag_cnt,
                                                          const ull* __restrict__ key_ws,
                                                          const float* __restrict__ xsq_ws,
                                                          float* __restrict__ out,
                                                          ull* __restrict__ loss_acc) {
    __shared__ int sOld;
    int n1 = *flag_cnt; if (n1 > CAP1) n1 = CAP1;
    const int t = threadIdx.x;

    for (int p = blockIdx.x; p < n1; p += gridDim.x) {
        const ull key = key_ws[p];
        const int idx = (int)(key & 0xFFFFFFFFu);
        const float d = finv((unsigned)(key >> 32));
        const int row = flag_list[p];
        const int bb = row >> 15, sp = row & (SPATIAL - 1);

        if (t == 0) sOld = (int)out[IDX_OFF + row];   // score's pick (this launch)
        __syncthreads();
        const int oldidx = sOld;

        if (t == 0) {
            atomicAdd(loss_acc, (ull)llrintf((d + xsq_ws[p]) * LSCALE));
            if (idx != oldidx) out[IDX_OFF + row] = (float)idx;
        }
        if (idx != oldidx)                             // rewrite q only on flip
            out[(size_t)bb * CDIM * SPATIAL + (size_t)t * SPATIAL + sp] =
                emb[(size_t)idx * CDIM + t];
        __syncthreads();                               // sOld reuse
    }
}

// ---- finalize: fixed-point -> float loss ------------------------------------
__global__ void finalize_kernel(const ull* __restrict__ loss_acc,
                                float* __restrict__ out) {
    double s = (double)*loss_acc / (double)LSCALE;
    out[LOSS_OFF] = (float)(0.25 * s / (double)Q_SIZE);
}

extern "C" void kernel_launch(void* const* d_in, const int* in_sizes, int n_in,
                              void* d_out, int out_size, void* d_ws, size_t ws_size,
                              hipStream_t stream) {
    const float* in = (const float*)d_in[0];
    const float* emb = (const float*)d_in[1];
    float* out = (float*)d_out;

    float* esq = (float*)d_ws;                                  // 4096 f32 (16 KB)
    uint4* Bpk16 = (uint4*)(esq + 4096);                        // 16384 uint4 (256 KB)
    float* ecT = (float*)(Bpk16 + 16384);                       // 128*1024 f32 (512 KB)
    ull* key_ws = (ull*)(ecT + CDIM * KCODES);                  // CAP1 ull (96 KB)
    float* xsq_ws = (float*)(key_ws + CAP1);                    // CAP1 f32 (48 KB)
    float* xrow_ws = xsq_ws + CAP1;                             // CAP1*128 f32 (6 MB)
    ull* loss_acc = (ull*)(xrow_ws + (size_t)CAP1 * CDIM);      // 8 B
    int* flag_cnt = (int*)(loss_acc + 1);
    int* flag_list = flag_cnt + 1;                              // CAP1 i32

    prep_kernel<<<128, 256, 0, stream>>>(emb, Bpk16, ecT, esq, out,
                                         loss_acc, flag_cnt);
    score_kernel<<<NROWS / 128, 256, 0, stream>>>(in, Bpk16, esq, emb, out,
                                                  flag_list, flag_cnt,
                                                  key_ws, xsq_ws, loss_acc);
    xgather_kernel<<<CAP1 / 2, 256, 0, stream>>>(in, flag_list, flag_cnt, xrow_ws);
    refine_scan_kernel<<<(CAP1 / RB_ROWS) * NCHUNK, 256, 0, stream>>>(
        xrow_ws, ecT, esq, flag_cnt, key_ws);
    refine_emit_kernel<<<2048, 128, 0, stream>>>(emb, flag_list, flag_cnt,
                                                 key_ws, xsq_ws, out, loss_acc);
    finalize_kernel<<<1, 1, 0, stream>>>(loss_acc, out);
}